// Round 20
// baseline (61.159 us; speedup 1.0000x reference)
//
#include <hip/hip_runtime.h>
#include <cstddef>
#include <cstdint>

// Problem constants
#define Bb   32
#define Ss   512
#define Dd   768
#define Ww   256
#define Pp   1024
#define NH   300            // hidden
#define SLOT1 320           // slot-1 column base (128B-aligned)
#define NPAD 640            // padded proj row: [0,300) slot0, [320,620) slot1
#define Mm   (Bb * Ww)      // 8192 words
#define ZROW 8192           // zero row index in each proj buffer
#define ZOFF (ZROW * NPAD)  // element offset of zero row
#define PBUF ((Mm + 1) * NPAD)   // elements per proj partial buffer (8193 rows)
#define KH   384            // K half

typedef __attribute__((ext_vector_type(8))) short bf16x8;
typedef __attribute__((ext_vector_type(4))) float f32x4;

#define GPTR(p) ((const __attribute__((address_space(1))) void*)(p))
#define LPTR(p) ((__attribute__((address_space(3))) void*)(p))

__device__ __forceinline__ unsigned short f2bf(float x) {
    unsigned u = __builtin_bit_cast(unsigned, x);
    u += 0x7fffu + ((u >> 16) & 1u);          // RNE
    return (unsigned short)(u >> 16);
}
__device__ __forceinline__ float bf2f(unsigned short u) {
    return __builtin_bit_cast(float, (unsigned)u << 16);
}
__device__ __forceinline__ unsigned pk2(float a, float b) {
    return (unsigned)f2bf(a) | ((unsigned)f2bf(b) << 16);
}
__device__ __forceinline__ float fast_tanh(float x) {
    x = fminf(fmaxf(x, -15.0f), 15.0f);
    float e = __expf(2.0f * x);
    return 1.0f - 2.0f * __builtin_amdgcn_rcpf(e + 1.0f);
}

// -------------------------------------------------------------------------
// Kernel 1 (mini-prep), grid-stride 512x256 (R13-identical):
//   (a) repack w1 -> BmatT bf16 (SLOT1 layout)
//   (b) zero row 8192 of both proj partial buffers
// -------------------------------------------------------------------------
__global__ __launch_bounds__(256) void prep_kernel(
    const float* __restrict__ w1, unsigned short* __restrict__ bmatT,
    unsigned short* __restrict__ proj)
{
    const int gid    = blockIdx.x * 256 + threadIdx.x;
    const int stride = 512 * 256;

    for (int u = gid; u < Dd * NPAD; u += stride) {
        const int k = u / NPAD;
        const int n = u - k * NPAD;
        float v = 0.0f;
        if (n < NH)                            v = w1[(size_t)k * NH + n];
        else if (n >= SLOT1 && n < SLOT1 + NH) v = w1[(size_t)(Dd + k) * NH + (n - SLOT1)];
        bmatT[(size_t)n * Dd + k] = f2bf(v);
    }

    if (gid < NPAD / 4) {
        *(ushort4*)(proj + ZOFF + gid * 4)        = make_ushort4(0, 0, 0, 0);
        *(ushort4*)(proj + PBUF + ZOFF + gid * 4) = make_ushort4(0, 0, 0, 0);
    }
}

// -------------------------------------------------------------------------
// Kernel 2: FUSED pool + MFMA bf16 GEMM, K-SPLIT x2 (R13 structure) +
// XOR-SWIZZLED A-LDS (T2, both write and read sides — rule #21):
//   addr(kb,row) = kb*2048 + ((row*16) ^ (kb<<5))
// Kills POOLW's 1.47M ds_write bank-conflict cycles (all kb groups were
// 2048B-stride = bank 0). Read side: XOR-by-constant within each 256B
// fr-block — bijective, 16B-aligned, same bank pattern as linear.
// 640 blocks. Tile 128x128, BK=32, 12 K-steps, 4 waves (2x2), wave 64x64.
// Bijective XCD swizzle (640 = 8*80), kh-major.
// -------------------------------------------------------------------------
__global__ __launch_bounds__(256) void gemm_kernel(
    const float* __restrict__ h,
    const int* __restrict__ word_start, const int* __restrict__ word_len,
    const unsigned short* __restrict__ bmatT,
    unsigned short* __restrict__ proj)
{
    __shared__ bf16x8 Al[2][4][128];   // 16 KB (pooled A; buf stride 8192 B)
    __shared__ bf16x8 Bl[2][4][128];   // 16 KB

    const int bid = blockIdx.x;
    const int t   = threadIdx.x;

    // bijective XCD swizzle over 640 = 8 XCDs x 80; kh-major within swz
    const int swz   = (bid & 7) * 80 + (bid >> 3);
    const int kh    = swz / 320;            // 0,1
    const int tIdx  = swz - kh * 320;
    const int mBase = (tIdx / 5) * 128;
    const int nBase = (tIdx % 5) * 128;
    const int kOff  = kh * KH;

    // ---- A staging roles (coalesced): row = (t>>3) + p*32, chunk = t&7
    const int srow_s = t >> 3;              // 0..31
    const int chunk  = t & 7;
    const int kbw    = chunk >> 1;          // write kb 0..3
    const int half8  = (chunk & 1) * 8;
    const float* hpA[4];
    const float* hpB[4];
#pragma unroll
    for (int p = 0; p < 4; ++p) {
        const int arow = mBase + srow_s + p * 32;      // word id (tile in 1 batch)
        const int s0   = word_start[arow];
        const int len  = word_len[arow];
        const float* base = h + (size_t)(arow >> 8) * (Ss * Dd)
                              + (size_t)s0 * Dd + kOff + chunk * 4;
        hpA[p] = base;
        hpB[p] = base + (size_t)(len - 1) * Dd;
    }

    // ---- B staging roles: col = t&127, oct pair {t>>7, t>>7+2}
    const unsigned short* srcB =
        bmatT + (size_t)(nBase + (t & 127)) * Dd + kOff + ((t >> 7) << 3);
    char* ldsB = (char*)&Bl[0][0][0] + t * 16;

    // ---- compute roles
    const int lane = t & 63;
    const int w    = t >> 6;
    const int wr   = w >> 1;
    const int wc   = w & 1;
    const int fr   = lane & 15;
    const int kb   = lane >> 4;

    f32x4 acc[4][4];
#pragma unroll
    for (int i = 0; i < 4; ++i)
#pragma unroll
        for (int j = 0; j < 4; ++j)
#pragma unroll
            for (int r = 0; r < 4; ++r) acc[i][j][r] = 0.0f;

    float4 hx[4], hy[4];

#define HLOAD(k0_)                                                        \
    {                                                                     \
        _Pragma("unroll")                                                 \
        for (int p = 0; p < 4; ++p) {                                     \
            hx[p] = *(const float4*)(hpA[p] + (k0_));                     \
            hy[p] = *(const float4*)(hpB[p] + (k0_));                     \
        }                                                                 \
    }

// swizzled A write: addr(kbw, row) = kbw*2048 + ((row*16) ^ (kbw<<5)) + half8
#define POOLW(c)                                                          \
    {                                                                     \
        _Pragma("unroll")                                                 \
        for (int p = 0; p < 4; ++p) {                                     \
            uint2 o;                                                      \
            o.x = pk2((hx[p].x + hy[p].x) * 0.5f,                         \
                      (hx[p].y + hy[p].y) * 0.5f);                        \
            o.y = pk2((hx[p].z + hy[p].z) * 0.5f,                         \
                      (hx[p].w + hy[p].w) * 0.5f);                        \
            const int rowb = (srow_s + p * 32) * 16;                      \
            *(uint2*)((char*)&Al[0][0][0] + (c) * 8192 + kbw * 2048       \
                      + (rowb ^ (kbw << 5)) + half8) = o;                 \
        }                                                                 \
    }

#define STAGEB(c, off)                                                                         \
    __builtin_amdgcn_global_load_lds(GPTR(srcB + (off)),      LPTR(ldsB + (c) * 8192),        16, 0, 0); \
    __builtin_amdgcn_global_load_lds(GPTR(srcB + (off) + 16), LPTR(ldsB + (c) * 8192 + 4096), 16, 0, 0)

// swizzled A read: same addr formula with (kb, wr*64+mi*16+fr)
#define COMPUTE(c)                                                                             \
    {                                                                                          \
        bf16x8 a[4], b[4];                                                                     \
        _Pragma("unroll")                                                                      \
        for (int mi = 0; mi < 4; ++mi) {                                                       \
            const int rowb = (wr * 64 + mi * 16 + fr) * 16;                                    \
            a[mi] = *(const bf16x8*)((char*)&Al[0][0][0] + (c) * 8192 + kb * 2048              \
                                     + (rowb ^ (kb << 5)));                                    \
        }                                                                                      \
        _Pragma("unroll")                                                                      \
        for (int ni = 0; ni < 4; ++ni) b[ni] = Bl[c][kb][wc * 64 + ni * 16 + fr];              \
        _Pragma("unroll")                                                                      \
        for (int mi = 0; mi < 4; ++mi)                                                         \
            _Pragma("unroll")                                                                  \
            for (int ni = 0; ni < 4; ++ni)                                                     \
                acc[mi][ni] = __builtin_amdgcn_mfma_f32_16x16x32_bf16(a[mi], b[ni], acc[mi][ni], 0, 0, 0); \
    }

    // prologue: fill buffer 0
    HLOAD(0);
    STAGEB(0, 0);
    POOLW(0);
    __syncthreads();                 // drains vmcnt(0): buf0 (A + B) ready

    int cur = 0;
    for (int k0 = 32; k0 < KH; k0 += 32) {
        HLOAD(k0);                   // h loads first (oldest in vmcnt queue)
        STAGEB(cur ^ 1, k0);         // B direct-to-LDS, drains at barrier
        COMPUTE(cur);                // MFMA on current buffer meanwhile
        POOLW(cur ^ 1);              // waits only the (older) h loads
        __syncthreads();
        cur ^= 1;
    }
    COMPUTE(cur);
#undef HLOAD
#undef POOLW
#undef STAGEB
#undef COMPUTE

    // C/D layout: col = lane&15, row = (lane>>4)*4 + r   [verified m89/m91]
    unsigned short* projh = proj + (size_t)kh * PBUF;
    const int r0 = mBase + wr * 64 + kb * 4;
    const int c0 = nBase + wc * 64 + fr;
#pragma unroll
    for (int mi = 0; mi < 4; ++mi)
#pragma unroll
        for (int ni = 0; ni < 4; ++ni)
#pragma unroll
            for (int r = 0; r < 4; ++r)
                projh[(size_t)(r0 + mi * 16 + r) * NPAD + c0 + ni * 16] = f2bf(acc[mi][ni][r]);
}

// -------------------------------------------------------------------------
// Kernel 3: 4 pairs per wave; gathers BOTH K-partials (proj0+proj1, summed
// before tanh); LDS-tree reduce + wave-parallel softmax. (R13-identical.)
// -------------------------------------------------------------------------
__global__ __launch_bounds__(256) void mlp_kernel(
    const unsigned short* __restrict__ proj,
    const float* __restrict__ b1, const float* __restrict__ w2,
    const float* __restrict__ b2, const int* __restrict__ pair_idx,
    float* __restrict__ out)
{
    __shared__ float red[4][64][17];   // [wave][src lane][16 outputs + pad]

    const int wv   = threadIdx.x >> 6;
    const int wave = blockIdx.x * 4 + wv;                   // 0..8191
    const int lane = threadIdx.x & 63;
    const int wid0 = wave * 4;                              // 4 pairs, same batch
    const int b    = wid0 >> 10;
    const int rbase = b * Ww * NPAD;
    const unsigned short* proj1 = proj + PBUF;

    const int4 piA = *(const int4*)(pair_idx + wid0 * 2);
    const int4 piB = *(const int4*)(pair_idx + wid0 * 2 + 4);
    const int idx[8] = {piA.x, piA.y, piA.z, piA.w, piB.x, piB.y, piB.z, piB.w};

    int off0[4], off1[4];
#pragma unroll
    for (int p = 0; p < 4; ++p) {
        const int i0 = idx[p * 2], i1 = idx[p * 2 + 1];
        off0[p] = (i0 >= 0) ? rbase + i0 * NPAD : ZOFF;
        off1[p] = ((i1 >= 0) ? rbase + i1 * NPAD : ZOFF) + SLOT1;
    }

    // issue all 80 gathers up front (coalesced 128B per instr)
    unsigned short g0a[4][5], g0b[4][5], g1a[4][5], g1b[4][5];
#pragma unroll
    for (int p = 0; p < 4; ++p)
#pragma unroll
        for (int it = 0; it < 5; ++it) {
            const int j = lane + it * 64;     // j<320; cols [300,320) are zero
            g0a[p][it] = proj [(size_t)off0[p] + j];
            g0b[p][it] = proj1[(size_t)off0[p] + j];
            g1a[p][it] = proj [(size_t)off1[p] + j];
            g1b[p][it] = proj1[(size_t)off1[p] + j];
        }

    float acc[4][4];
#pragma unroll
    for (int p = 0; p < 4; ++p)
#pragma unroll
        for (int c = 0; c < 4; ++c) acc[p][c] = 0.0f;

#pragma unroll
    for (int it = 0; it < 5; ++it) {
        const int j  = lane + it * 64;
        const bool ok = (j < NH);
        const float bj = ok ? b1[j] : 0.0f;
        float4 wv4 = make_float4(0.f, 0.f, 0.f, 0.f);
        if (ok) wv4 = *(const float4*)(w2 + (size_t)j * 4);
#pragma unroll
        for (int p = 0; p < 4; ++p) {
            const float v = bj + (bf2f(g0a[p][it]) + bf2f(g0b[p][it]))
                               + (bf2f(g1a[p][it]) + bf2f(g1b[p][it]));
            const float x = ok ? fast_tanh(v) : 0.0f;
            acc[p][0] = fmaf(x, wv4.x, acc[p][0]);
            acc[p][1] = fmaf(x, wv4.y, acc[p][1]);
            acc[p][2] = fmaf(x, wv4.z, acc[p][2]);
            acc[p][3] = fmaf(x, wv4.w, acc[p][3]);
        }
    }

#pragma unroll
    for (int p = 0; p < 4; ++p)
#pragma unroll
        for (int c = 0; c < 4; ++c)
            red[wv][lane][p * 4 + c] = acc[p][c];
    __syncthreads();

    const int o = lane >> 2;          // output id = p*4+c
    const int g = lane & 3;           // source quarter
    float v = 0.0f;
#pragma unroll
    for (int i = 0; i < 16; ++i)
        v += red[wv][g * 16 + i][o];
    v += __shfl_xor(v, 1, 64);
    v += __shfl_xor(v, 2, 64);

    const int c = o & 3;
    const float l = v + b2[c];
    float mx = fmaxf(l, __shfl_xor(l, 4, 64));
    mx = fmaxf(mx, __shfl_xor(mx, 8, 64));
    const float e = __expf(l - mx);
    float s = e + __shfl_xor(e, 4, 64);
    s += __shfl_xor(s, 8, 64);
    const float r = e * __builtin_amdgcn_rcpf(s);
    if (g == 0)
        out[(size_t)(wid0 + (o >> 2)) * 4 + c] = r;
}

// -------------------------------------------------------------------------
extern "C" void kernel_launch(void* const* d_in, const int* in_sizes, int n_in,
                              void* d_out, int out_size, void* d_ws, size_t ws_size,
                              hipStream_t stream)
{
    const float* h          = (const float*)d_in[0];
    const float* w1         = (const float*)d_in[1];
    const float* b1         = (const float*)d_in[2];
    const float* w2         = (const float*)d_in[3];
    const float* b2         = (const float*)d_in[4];
    const int*   word_start = (const int*)d_in[5];
    const int*   word_len   = (const int*)d_in[6];
    const int*   pair_idx   = (const int*)d_in[7];
    float*       out        = (float*)d_out;

    // workspace layout (all bf16)
    unsigned short* proj  = (unsigned short*)d_ws;   // 2 partial bufs, 8193x640 each = 20,974,080 B
    unsigned short* bmatT = (unsigned short*)((char*)d_ws + 20975616);   // 983,040 B

    prep_kernel<<<dim3(512),  dim3(256), 0, stream>>>(w1, bmatT, proj);
    gemm_kernel<<<dim3(640),  dim3(256), 0, stream>>>(h, word_start, word_len, bmatT, proj);
    mlp_kernel <<<dim3(2048), dim3(256), 0, stream>>>(proj, b1, w2, b2, pair_idx, out);
}

// Round 21
// 50.275 us; speedup vs baseline: 1.2165x; 1.2165x over previous
//
#include <hip/hip_runtime.h>
#include <cstddef>
#include <cstdint>

// Problem constants
#define Bb   32
#define Ss   512
#define Dd   768
#define Ww   256
#define Pp   1024
#define NH   300            // hidden
#define SLOT1 320           // slot-1 column base (128B-aligned)
#define NPAD 640            // padded proj row: [0,300) slot0, [320,620) slot1
#define Mm   (Bb * Ww)      // 8192 words
#define ZROW 8192           // zero row index in each proj buffer
#define ZOFF (ZROW * NPAD)  // element offset of zero row
#define PBUF ((Mm + 1) * NPAD)   // elements per proj partial buffer (8193 rows)
#define KH   384            // K half

typedef __attribute__((ext_vector_type(8))) short bf16x8;
typedef __attribute__((ext_vector_type(4))) float f32x4;

#define GPTR(p) ((const __attribute__((address_space(1))) void*)(p))
#define LPTR(p) ((__attribute__((address_space(3))) void*)(p))

__device__ __forceinline__ unsigned short f2bf(float x) {
    unsigned u = __builtin_bit_cast(unsigned, x);
    u += 0x7fffu + ((u >> 16) & 1u);          // RNE
    return (unsigned short)(u >> 16);
}
__device__ __forceinline__ float bf2f(unsigned short u) {
    return __builtin_bit_cast(float, (unsigned)u << 16);
}
__device__ __forceinline__ unsigned pk2(float a, float b) {
    return (unsigned)f2bf(a) | ((unsigned)f2bf(b) << 16);
}
__device__ __forceinline__ float fast_tanh(float x) {
    x = fminf(fmaxf(x, -15.0f), 15.0f);
    float e = __expf(2.0f * x);
    return 1.0f - 2.0f * __builtin_amdgcn_rcpf(e + 1.0f);
}

// -------------------------------------------------------------------------
// Kernel 1 (mini-prep), grid-stride 512x256:
//   (a) repack w1 -> BmatT bf16:
//       BmatT[n][k] = n<300 ? w1[k][n] : (320<=n<620 ? w1[768+k][n-320] : 0)
//   (b) zero row 8192 of both proj partial buffers
// -------------------------------------------------------------------------
__global__ __launch_bounds__(256) void prep_kernel(
    const float* __restrict__ w1, unsigned short* __restrict__ bmatT,
    unsigned short* __restrict__ proj)
{
    const int gid    = blockIdx.x * 256 + threadIdx.x;
    const int stride = 512 * 256;

    for (int u = gid; u < Dd * NPAD; u += stride) {
        const int k = u / NPAD;
        const int n = u - k * NPAD;
        float v = 0.0f;
        if (n < NH)                            v = w1[(size_t)k * NH + n];
        else if (n >= SLOT1 && n < SLOT1 + NH) v = w1[(size_t)(Dd + k) * NH + (n - SLOT1)];
        bmatT[(size_t)n * Dd + k] = f2bf(v);
    }

    if (gid < NPAD / 4) {
        *(ushort4*)(proj + ZOFF + gid * 4)        = make_ushort4(0, 0, 0, 0);
        *(ushort4*)(proj + PBUF + ZOFF + gid * 4) = make_ushort4(0, 0, 0, 0);
    }
}

// -------------------------------------------------------------------------
// Kernel 2: FUSED pool + MFMA bf16 GEMM, K-SPLIT x2 (R13 winner, verbatim):
//   proj[kh][8192][640] (bf16 partials) = mean-pool(h)[:, kh*384:(kh+1)*384]
//                                          @ Bmat[kh*384:(kh+1)*384, :]
// 640 blocks (2.5/CU). Tile 128x128, BK=32, 12 K-steps. 4 waves (2x2),
// wave 64x64 (4x4 frags). A reg-staged COALESCED (lane -> (row=t>>3,
// chunk=t&7): 8 x 128B lines per wave-load), pooled in-flight, ds_write 8B.
// B via global_load_lds width-16 (linear dest). Double-buffered LDS.
// Bijective XCD swizzle (640 = 8*80), kh-major so same-XCD blocks share A/B.
// -------------------------------------------------------------------------
__global__ __launch_bounds__(256) void gemm_kernel(
    const float* __restrict__ h,
    const int* __restrict__ word_start, const int* __restrict__ word_len,
    const unsigned short* __restrict__ bmatT,
    unsigned short* __restrict__ proj)
{
    __shared__ bf16x8 Al[2][4][128];   // 16 KB
    __shared__ bf16x8 Bl[2][4][128];   // 16 KB

    const int bid = blockIdx.x;
    const int t   = threadIdx.x;

    // bijective XCD swizzle over 640 = 8 XCDs x 80; kh-major within swz
    const int swz   = (bid & 7) * 80 + (bid >> 3);
    const int kh    = swz / 320;            // 0,1
    const int tIdx  = swz - kh * 320;
    const int mBase = (tIdx / 5) * 128;
    const int nBase = (tIdx % 5) * 128;
    const int kOff  = kh * KH;

    // ---- A staging roles (coalesced): srow_s = t>>3 (0..31), chunk = t&7
    const int srow_s = t >> 3;
    const int chunk  = t & 7;
    const float* hpA[4];
    const float* hpB[4];
#pragma unroll
    for (int p = 0; p < 4; ++p) {
        const int arow = mBase + srow_s + p * 32;      // word id (tile in 1 batch)
        const int s0   = word_start[arow];
        const int len  = word_len[arow];
        const float* base = h + (size_t)(arow >> 8) * (Ss * Dd)
                              + (size_t)s0 * Dd + kOff + chunk * 4;
        hpA[p] = base;
        hpB[p] = base + (size_t)(len - 1) * Dd;
    }
    // A LDS dest byte (per pass p adds p*32 rows): kb = chunk>>1, half = chunk&1
    const int aByte = (chunk >> 1) * 2048 + srow_s * 16 + (chunk & 1) * 8;

    // ---- B staging roles: col = t&127, oct pair {skb, skb+2}, skb = t>>7
    const unsigned short* srcB =
        bmatT + (size_t)(nBase + (t & 127)) * Dd + kOff + ((t >> 7) << 3);
    char* ldsB = (char*)&Bl[0][0][0] + t * 16;

    // ---- compute roles
    const int lane = t & 63;
    const int w    = t >> 6;
    const int wr   = w >> 1;
    const int wc   = w & 1;
    const int fr   = lane & 15;
    const int kb   = lane >> 4;

    f32x4 acc[4][4];
#pragma unroll
    for (int i = 0; i < 4; ++i)
#pragma unroll
        for (int j = 0; j < 4; ++j)
#pragma unroll
            for (int r = 0; r < 4; ++r) acc[i][j][r] = 0.0f;

    float4 hx[4], hy[4];

#define HLOAD(k0_)                                                        \
    {                                                                     \
        _Pragma("unroll")                                                 \
        for (int p = 0; p < 4; ++p) {                                     \
            hx[p] = *(const float4*)(hpA[p] + (k0_));                     \
            hy[p] = *(const float4*)(hpB[p] + (k0_));                     \
        }                                                                 \
    }

#define POOLW(c)                                                          \
    {                                                                     \
        _Pragma("unroll")                                                 \
        for (int p = 0; p < 4; ++p) {                                     \
            uint2 o;                                                      \
            o.x = pk2((hx[p].x + hy[p].x) * 0.5f,                         \
                      (hx[p].y + hy[p].y) * 0.5f);                        \
            o.y = pk2((hx[p].z + hy[p].z) * 0.5f,                         \
                      (hx[p].w + hy[p].w) * 0.5f);                        \
            *(uint2*)((char*)&Al[0][0][0] + (c) * 8192 + aByte            \
                      + p * (32 * 16)) = o;                               \
        }                                                                 \
    }

#define STAGEB(c, off)                                                                         \
    __builtin_amdgcn_global_load_lds(GPTR(srcB + (off)),      LPTR(ldsB + (c) * 8192),        16, 0, 0); \
    __builtin_amdgcn_global_load_lds(GPTR(srcB + (off) + 16), LPTR(ldsB + (c) * 8192 + 4096), 16, 0, 0)

#define COMPUTE(c)                                                                             \
    {                                                                                          \
        bf16x8 a[4], b[4];                                                                     \
        _Pragma("unroll")                                                                      \
        for (int mi = 0; mi < 4; ++mi) a[mi] = Al[c][kb][wr * 64 + mi * 16 + fr];              \
        _Pragma("unroll")                                                                      \
        for (int ni = 0; ni < 4; ++ni) b[ni] = Bl[c][kb][wc * 64 + ni * 16 + fr];              \
        _Pragma("unroll")                                                                      \
        for (int mi = 0; mi < 4; ++mi)                                                         \
            _Pragma("unroll")                                                                  \
            for (int ni = 0; ni < 4; ++ni)                                                     \
                acc[mi][ni] = __builtin_amdgcn_mfma_f32_16x16x32_bf16(a[mi], b[ni], acc[mi][ni], 0, 0, 0); \
    }

    // prologue: fill buffer 0
    HLOAD(0);
    STAGEB(0, 0);
    POOLW(0);
    __syncthreads();                 // drains vmcnt(0): buf0 (A + B) ready

    int cur = 0;
    for (int k0 = 32; k0 < KH; k0 += 32) {
        HLOAD(k0);                   // h loads first (oldest in vmcnt queue)
        STAGEB(cur ^ 1, k0);         // B direct-to-LDS, drains at barrier
        COMPUTE(cur);                // MFMA on current buffer meanwhile
        POOLW(cur ^ 1);              // waits only the (older) h loads
        __syncthreads();
        cur ^= 1;
    }
    COMPUTE(cur);
#undef HLOAD
#undef POOLW
#undef STAGEB
#undef COMPUTE

    // C/D layout: col = lane&15, row = (lane>>4)*4 + r   [verified m89/m91]
    unsigned short* projh = proj + (size_t)kh * PBUF;
    const int r0 = mBase + wr * 64 + kb * 4;
    const int c0 = nBase + wc * 64 + fr;
#pragma unroll
    for (int mi = 0; mi < 4; ++mi)
#pragma unroll
        for (int ni = 0; ni < 4; ++ni)
#pragma unroll
            for (int r = 0; r < 4; ++r)
                projh[(size_t)(r0 + mi * 16 + r) * NPAD + c0 + ni * 16] = f2bf(acc[mi][ni][r]);
}

// -------------------------------------------------------------------------
// Kernel 3: 4 pairs per wave; gathers BOTH K-partials (proj0+proj1, summed
// before tanh); LDS-tree reduce + wave-parallel softmax. (R13-identical.)
// -------------------------------------------------------------------------
__global__ __launch_bounds__(256) void mlp_kernel(
    const unsigned short* __restrict__ proj,
    const float* __restrict__ b1, const float* __restrict__ w2,
    const float* __restrict__ b2, const int* __restrict__ pair_idx,
    float* __restrict__ out)
{
    __shared__ float red[4][64][17];   // [wave][src lane][16 outputs + pad]

    const int wv   = threadIdx.x >> 6;
    const int wave = blockIdx.x * 4 + wv;                   // 0..8191
    const int lane = threadIdx.x & 63;
    const int wid0 = wave * 4;                              // 4 pairs, same batch
    const int b    = wid0 >> 10;
    const int rbase = b * Ww * NPAD;
    const unsigned short* proj1 = proj + PBUF;

    const int4 piA = *(const int4*)(pair_idx + wid0 * 2);
    const int4 piB = *(const int4*)(pair_idx + wid0 * 2 + 4);
    const int idx[8] = {piA.x, piA.y, piA.z, piA.w, piB.x, piB.y, piB.z, piB.w};

    int off0[4], off1[4];
#pragma unroll
    for (int p = 0; p < 4; ++p) {
        const int i0 = idx[p * 2], i1 = idx[p * 2 + 1];
        off0[p] = (i0 >= 0) ? rbase + i0 * NPAD : ZOFF;
        off1[p] = ((i1 >= 0) ? rbase + i1 * NPAD : ZOFF) + SLOT1;
    }

    // issue all 80 gathers up front (coalesced 128B per instr)
    unsigned short g0a[4][5], g0b[4][5], g1a[4][5], g1b[4][5];
#pragma unroll
    for (int p = 0; p < 4; ++p)
#pragma unroll
        for (int it = 0; it < 5; ++it) {
            const int j = lane + it * 64;     // j<320; cols [300,320) are zero
            g0a[p][it] = proj [(size_t)off0[p] + j];
            g0b[p][it] = proj1[(size_t)off0[p] + j];
            g1a[p][it] = proj [(size_t)off1[p] + j];
            g1b[p][it] = proj1[(size_t)off1[p] + j];
        }

    float acc[4][4];
#pragma unroll
    for (int p = 0; p < 4; ++p)
#pragma unroll
        for (int c = 0; c < 4; ++c) acc[p][c] = 0.0f;

#pragma unroll
    for (int it = 0; it < 5; ++it) {
        const int j  = lane + it * 64;
        const bool ok = (j < NH);
        const float bj = ok ? b1[j] : 0.0f;
        float4 wv4 = make_float4(0.f, 0.f, 0.f, 0.f);
        if (ok) wv4 = *(const float4*)(w2 + (size_t)j * 4);
#pragma unroll
        for (int p = 0; p < 4; ++p) {
            const float v = bj + (bf2f(g0a[p][it]) + bf2f(g0b[p][it]))
                               + (bf2f(g1a[p][it]) + bf2f(g1b[p][it]));
            const float x = ok ? fast_tanh(v) : 0.0f;
            acc[p][0] = fmaf(x, wv4.x, acc[p][0]);
            acc[p][1] = fmaf(x, wv4.y, acc[p][1]);
            acc[p][2] = fmaf(x, wv4.z, acc[p][2]);
            acc[p][3] = fmaf(x, wv4.w, acc[p][3]);
        }
    }

#pragma unroll
    for (int p = 0; p < 4; ++p)
#pragma unroll
        for (int c = 0; c < 4; ++c)
            red[wv][lane][p * 4 + c] = acc[p][c];
    __syncthreads();

    const int o = lane >> 2;          // output id = p*4+c
    const int g = lane & 3;           // source quarter
    float v = 0.0f;
#pragma unroll
    for (int i = 0; i < 16; ++i)
        v += red[wv][g * 16 + i][o];
    v += __shfl_xor(v, 1, 64);
    v += __shfl_xor(v, 2, 64);

    const int c = o & 3;
    const float l = v + b2[c];
    float mx = fmaxf(l, __shfl_xor(l, 4, 64));
    mx = fmaxf(mx, __shfl_xor(mx, 8, 64));
    const float e = __expf(l - mx);
    float s = e + __shfl_xor(e, 4, 64);
    s += __shfl_xor(s, 8, 64);
    const float r = e * __builtin_amdgcn_rcpf(s);
    if (g == 0)
        out[(size_t)(wid0 + (o >> 2)) * 4 + c] = r;
}

// -------------------------------------------------------------------------
extern "C" void kernel_launch(void* const* d_in, const int* in_sizes, int n_in,
                              void* d_out, int out_size, void* d_ws, size_t ws_size,
                              hipStream_t stream)
{
    const float* h          = (const float*)d_in[0];
    const float* w1         = (const float*)d_in[1];
    const float* b1         = (const float*)d_in[2];
    const float* w2         = (const float*)d_in[3];
    const float* b2         = (const float*)d_in[4];
    const int*   word_start = (const int*)d_in[5];
    const int*   word_len   = (const int*)d_in[6];
    const int*   pair_idx   = (const int*)d_in[7];
    float*       out        = (float*)d_out;

    // workspace layout (all bf16)
    unsigned short* proj  = (unsigned short*)d_ws;   // 2 partial bufs, 8193x640 each = 20,974,080 B
    unsigned short* bmatT = (unsigned short*)((char*)d_ws + 20975616);   // 983,040 B

    prep_kernel<<<dim3(512),  dim3(256), 0, stream>>>(w1, bmatT, proj);
    gemm_kernel<<<dim3(640),  dim3(256), 0, stream>>>(h, word_start, word_len, bmatT, proj);
    mlp_kernel <<<dim3(2048), dim3(256), 0, stream>>>(proj, b1, w2, b2, pair_idx, out);
}